// Round 5
// baseline (416.292 us; speedup 1.0000x reference)
//
#include <hip/hip_runtime.h>

#define N_NODES 100000
#define N_EDGES 50000
#define N_KEYS  150000   // node keys [0,100000) then edge keys [100000,150000)
#define M_INC   1600000
#define D_HID   64
#define KREP    8

#define N_TILES_N 25   // ceil(100000/4096)
#define N_TILES_E 13   // ceil(50000/4096)

// ---- workspace layout (byte offsets, lifetime-overlapped) ----
// ranks    [1.6M u32]   @ 0
// noff     [100001 int] @ 6400000
// eoff     [ 50001 int] @ 6800016
// node_csr [1.6M int]   @ 7000032    (cnt8 [1.2M int, 4.8MB] overlaps here; dead before fill)
// edge_csr [1.6M int]   @ 13400032   (tot [150K int] overlaps here; dead before fill)
// ef       [3.2M float] @ 19800032   (rb [1.2M int] overlaps @ +0; scan scratch @ +5000000;
//                                     both dead before stage1 writes ef)

// Pass A: replica-spread counting. k = m&7; 2 device atomics per incidence,
// same-address contention depth cut 8x. Subranks packed into ranks[m].
__global__ void passA_kernel(const int* __restrict__ node_idx,
                             const int* __restrict__ edge_idx,
                             int* __restrict__ cnt8,
                             unsigned int* __restrict__ ranks) {
    int m = blockIdx.x * 256 + threadIdx.x;
    if (m < M_INC) {
        int n = node_idx[m], e = edge_idx[m];
        int* base = cnt8 + (m & (KREP - 1)) * N_KEYS;
        unsigned pn = (unsigned)atomicAdd(&base[n], 1);
        unsigned pe = (unsigned)atomicAdd(&base[N_NODES + e], 1);
        ranks[m] = (pn << 16) | pe;
    }
}

// Per-key prefix over the 8 replica counts -> rb[k][key]; totals -> tot[key].
// Fully coalesced (fixed k => consecutive threads hit consecutive addresses).
__global__ void replprefix_kernel(const int* __restrict__ cnt8,
                                  int* __restrict__ rb, int* __restrict__ tot) {
    int key = blockIdx.x * 256 + threadIdx.x;
    if (key < N_KEYS) {
        int base = 0;
#pragma unroll
        for (int k = 0; k < KREP; k++) {
            rb[k * N_KEYS + key] = base;
            base += cnt8[k * N_KEYS + key];
        }
        tot[key] = base;
    }
}

// Scan stage 1: per-tile (4096 elements) sums over the contiguous totals array.
__global__ void scan_partial_kernel(const int* __restrict__ cnt,
                                    int* __restrict__ pn, int* __restrict__ pe) {
    __shared__ int lds[16];
    int b = blockIdx.x;
    const int* src; int nElem; int tile; int* dst;
    if (b < N_TILES_N) { src = cnt;            nElem = N_NODES; tile = b;             dst = pn; }
    else               { src = cnt + N_NODES;  nElem = N_EDGES; tile = b - N_TILES_N; dst = pe; }
    int t = threadIdx.x;
    int i4 = tile * 1024 + t;
    int sum = 0;
    if (i4 * 4 < nElem) {
        int4 v = ((const int4*)src)[i4];
        sum = v.x + v.y + v.z + v.w;
    }
    for (int off = 1; off < 64; off <<= 1) sum += __shfl_xor(sum, off, 64);
    if ((t & 63) == 0) lds[t >> 6] = sum;
    __syncthreads();
    if (t < 16) {
        int s = lds[t];
        for (int off = 1; off < 16; off <<= 1) s += __shfl_xor(s, off, 64);
        if (t == 0) dst[tile] = s;
    }
}

// Scan stage 2: exclusive scan of tile sums; writes sentinel offsets.
__global__ void scan_base_kernel(const int* __restrict__ pn, const int* __restrict__ pe,
                                 int* __restrict__ bn, int* __restrict__ be,
                                 int* __restrict__ noff, int* __restrict__ eoff) {
    int w = threadIdx.x >> 6;
    int lane = threadIdx.x & 63;
    if (w == 0) {
        int v = (lane < N_TILES_N) ? pn[lane] : 0;
        int incl = v;
        for (int d = 1; d < 64; d <<= 1) { int u = __shfl_up(incl, d, 64); if (lane >= d) incl += u; }
        if (lane < N_TILES_N) bn[lane] = incl - v;
        if (lane == N_TILES_N - 1) noff[N_NODES] = incl;
    } else {
        int v = (lane < N_TILES_E) ? pe[lane] : 0;
        int incl = v;
        for (int d = 1; d < 64; d <<= 1) { int u = __shfl_up(incl, d, 64); if (lane >= d) incl += u; }
        if (lane < N_TILES_E) be[lane] = incl - v;
        if (lane == N_TILES_E - 1) eoff[N_EDGES] = incl;
    }
}

// Scan stage 3: block-level exclusive scan of each tile + tile base, int4 I/O.
__global__ void scan_write_kernel(const int* __restrict__ cnt,
                                  const int* __restrict__ bn, const int* __restrict__ be,
                                  int* __restrict__ noff, int* __restrict__ eoff) {
    __shared__ int wsum[16];
    int b = blockIdx.x;
    const int* src; int* dst; int nElem; int tile; int tbase;
    if (b < N_TILES_N) { src = cnt;           dst = noff; nElem = N_NODES; tile = b;             tbase = bn[tile]; }
    else               { src = cnt + N_NODES; dst = eoff; nElem = N_EDGES; tile = b - N_TILES_N; tbase = be[tile]; }
    int t = threadIdx.x;
    int lane = t & 63, w = t >> 6;
    int i4 = tile * 1024 + t;
    int4 c = make_int4(0, 0, 0, 0);
    bool valid = (i4 * 4 < nElem);
    if (valid) c = ((const int4*)src)[i4];
    int tsum = c.x + c.y + c.z + c.w;
    int incl = tsum;
    for (int d = 1; d < 64; d <<= 1) { int u = __shfl_up(incl, d, 64); if (lane >= d) incl += u; }
    if (lane == 63) wsum[w] = incl;
    __syncthreads();
    if (t < 16) {
        int v = wsum[t];
        int wi = v;
        for (int d = 1; d < 16; d <<= 1) { int u = __shfl_up(wi, d, 64); if (t >= d) wi += u; }
        wsum[t] = wi - v;
    }
    __syncthreads();
    int ex = tbase + wsum[w] + incl - tsum;
    if (valid) {
        int4 o;
        o.x = ex; o.y = ex + c.x; o.z = o.y + c.y; o.w = o.z + c.z;
        ((int4*)dst)[i4] = o;
    }
}

// Fill: atomic-free scatter. Global slot = seg_off + replica_base + subrank.
__global__ void fill_kernel(const int* __restrict__ node_idx,
                            const int* __restrict__ edge_idx,
                            const unsigned int* __restrict__ ranks,
                            const int* __restrict__ rb,
                            const int* __restrict__ noff, const int* __restrict__ eoff,
                            int* __restrict__ node_csr, int* __restrict__ edge_csr) {
    int m = blockIdx.x * 256 + threadIdx.x;
    if (m < M_INC) {
        int n = node_idx[m], e = edge_idx[m];
        unsigned rp = ranks[m];
        const int* rbk = rb + (m & (KREP - 1)) * N_KEYS;
        edge_csr[eoff[e] + rbk[N_NODES + e] + (int)(rp & 0xffffu)] = n;
        node_csr[noff[n] + rbk[n] + (int)(rp >> 16)] = e;
    }
}

// Stage 1: one wave per edge; 4 member-groups x 16 lanes, float4 per lane.
__global__ void stage1_kernel(const int* __restrict__ eoff, const int* __restrict__ ecsr,
                              const float* __restrict__ x, float* __restrict__ ef) {
    int wid = (blockIdx.x * 256 + threadIdx.x) >> 6;
    if (wid >= N_EDGES) return;
    int lane = threadIdx.x & 63;
    int group = lane >> 4;
    int gl = lane & 15;
    int s = eoff[wid], t = eoff[wid + 1];
    float4 acc = make_float4(0.f, 0.f, 0.f, 0.f);
    for (int base = s; base < t; base += 64) {
        int idx_l = (base + lane < t) ? ecsr[base + lane] : 0;
        int cnt = t - base; if (cnt > 64) cnt = 64;
        int steps = (cnt + 3) >> 2;
        for (int j = 0; j < steps; j++) {
            int p = 4 * j + group;
            int mi = __shfl(idx_l, p, 64);
            if (p < cnt) {
                float4 v = ((const float4*)x)[(size_t)mi * 16 + gl];
                acc.x += v.x; acc.y += v.y; acc.z += v.z; acc.w += v.w;
            }
        }
    }
    for (int off = 16; off < 64; off <<= 1) {
        acc.x += __shfl_xor(acc.x, off, 64);
        acc.y += __shfl_xor(acc.y, off, 64);
        acc.z += __shfl_xor(acc.z, off, 64);
        acc.w += __shfl_xor(acc.w, off, 64);
    }
    if (group == 0) {
        int card = t - s;
        float ber = (card > 0) ? (1.0f / (float)card) : 0.f;
        ((float4*)ef)[(size_t)wid * 16 + gl] =
            make_float4(acc.x * ber, acc.y * ber, acc.z * ber, acc.w * ber);
    }
}

// Stage 2: one wave per node; Dn computed inline from ew gathers.
__global__ void stage2_kernel(const int* __restrict__ noff, const int* __restrict__ ncsr,
                              const float* __restrict__ ef, const float* __restrict__ ew,
                              const float* __restrict__ x, float* __restrict__ out) {
    int wid = (blockIdx.x * 256 + threadIdx.x) >> 6;
    if (wid >= N_NODES) return;
    int lane = threadIdx.x & 63;
    int group = lane >> 4;
    int gl = lane & 15;
    int s = noff[wid], t = noff[wid + 1];
    float4 acc = make_float4(0.f, 0.f, 0.f, 0.f);
    float dn = 0.f;
    for (int base = s; base < t; base += 64) {
        bool lv = (base + lane < t);
        int idx_l = lv ? ncsr[base + lane] : 0;
        if (lv) dn += ew[idx_l];
        int cnt = t - base; if (cnt > 64) cnt = 64;
        int steps = (cnt + 3) >> 2;
        for (int j = 0; j < steps; j++) {
            int p = 4 * j + group;
            int mi = __shfl(idx_l, p, 64);
            if (p < cnt) {
                float4 v = ((const float4*)ef)[(size_t)mi * 16 + gl];
                acc.x += v.x; acc.y += v.y; acc.z += v.z; acc.w += v.w;
            }
        }
    }
    for (int off = 1; off < 64; off <<= 1) dn += __shfl_xor(dn, off, 64);
    for (int off = 16; off < 64; off <<= 1) {
        acc.x += __shfl_xor(acc.x, off, 64);
        acc.y += __shfl_xor(acc.y, off, 64);
        acc.z += __shfl_xor(acc.z, off, 64);
        acc.w += __shfl_xor(acc.w, off, 64);
    }
    if (group == 0) {
        float dnr = (dn > 0.f) ? (1.0f / dn) : 0.f;
        float4 xv = ((const float4*)x)[(size_t)wid * 16 + gl];
        float4 r;
        r.x = 0.5f * (xv.x + dnr * acc.x);
        r.y = 0.5f * (xv.y + dnr * acc.y);
        r.z = 0.5f * (xv.z + dnr * acc.z);
        r.w = 0.5f * (xv.w + dnr * acc.w);
        ((float4*)out)[(size_t)wid * 16 + gl] = r;
    }
}

extern "C" void kernel_launch(void* const* d_in, const int* in_sizes, int n_in,
                              void* d_out, int out_size, void* d_ws, size_t ws_size,
                              hipStream_t stream) {
    const float* x        = (const float*)d_in[0];
    const int*   node_idx = (const int*)d_in[1];
    const int*   edge_idx = (const int*)d_in[2];
    const float* ew       = (const float*)d_in[3];
    float* out = (float*)d_out;

    char* ws = (char*)d_ws;
    unsigned int* ranks    = (unsigned int*)(ws + 0);
    int*          noff     = (int*)(ws + 6400000);
    int*          eoff     = (int*)(ws + 6800016);
    int*          node_csr = (int*)(ws + 7000032);
    int*          edge_csr = (int*)(ws + 13400032);
    float*        ef       = (float*)(ws + 19800032);
    // lifetime-overlapped scratch:
    int* cnt8 = (int*)(ws + 7000032);    // 4.8MB under node_csr; dead before fill
    int* tot  = (int*)(ws + 13400032);   // 600KB under edge_csr; dead before fill
    int* rb   = (int*)(ws + 19800032);   // 4.8MB under ef; dead before stage1
    int* pn   = (int*)(ws + 24800032);   // scan scratch under ef; dead before stage1
    int* pe   = pn + 32;
    int* bn   = pn + 64;
    int* be   = pn + 96;

    hipMemsetAsync(cnt8, 0, (size_t)KREP * N_KEYS * 4, stream);

    passA_kernel<<<(M_INC + 255) / 256, 256, 0, stream>>>(node_idx, edge_idx, cnt8, ranks);
    replprefix_kernel<<<(N_KEYS + 255) / 256, 256, 0, stream>>>(cnt8, rb, tot);
    scan_partial_kernel<<<N_TILES_N + N_TILES_E, 1024, 0, stream>>>(tot, pn, pe);
    scan_base_kernel<<<1, 128, 0, stream>>>(pn, pe, bn, be, noff, eoff);
    scan_write_kernel<<<N_TILES_N + N_TILES_E, 1024, 0, stream>>>(tot, bn, be, noff, eoff);
    fill_kernel<<<(M_INC + 255) / 256, 256, 0, stream>>>(node_idx, edge_idx, ranks, rb,
                                                         noff, eoff, node_csr, edge_csr);
    stage1_kernel<<<(N_EDGES * 64 + 255) / 256, 256, 0, stream>>>(eoff, edge_csr, x, ef);
    stage2_kernel<<<(N_NODES * 64 + 255) / 256, 256, 0, stream>>>(noff, node_csr, ef, ew, x, out);
}

// Round 6
// 387.439 us; speedup vs baseline: 1.0745x; 1.0745x over previous
//
#include <hip/hip_runtime.h>

#define N_NODES 100000
#define N_EDGES 50000
#define N_KEYS  150000   // node keys [0,100000) then edge keys [100000,150000)
#define M_INC   1600000
#define D_HID   64
#define KREP    8        // == number of XCDs

#define N_TILES_N 25   // ceil(100000/4096)
#define N_TILES_E 13   // ceil(50000/4096)

// ---- workspace layout (byte offsets, lifetime-overlapped) ----
// ranks    [1.6M u32]   @ 0              (xcc<<26 | rank_n<<13 | rank_e)
// noff     [100001 int] @ 6400000
// eoff     [ 50001 int] @ 6800016
// node_csr [1.6M int]   @ 7000032    (cnt8 [1.2M int] overlaps; dead before fill)
// edge_csr [1.6M int]   @ 13400032   (tot [150K int] overlaps; dead before fill)
// ef       [3.2M float] @ 19800032   (rb + scan scratch overlap; dead before stage1)

// Pass A: per-XCD replica counting with XCD-local (workgroup-scope) atomics.
// All updaters of replica k run on XCD k => RMW resolves in that XCD's L2,
// never crossing to the device coherent point. Subranks + replica id packed
// into ranks[m].
__global__ void passA_kernel(const int* __restrict__ node_idx,
                             const int* __restrict__ edge_idx,
                             int* __restrict__ cnt8,
                             unsigned int* __restrict__ ranks) {
    unsigned xcc;
    asm volatile("s_getreg_b32 %0, hwreg(HW_REG_XCC_ID)" : "=s"(xcc));
    xcc &= (KREP - 1);
    int* base = cnt8 + xcc * N_KEYS;
    int m = blockIdx.x * 256 + threadIdx.x;
    if (m < M_INC) {
        int n = node_idx[m], e = edge_idx[m];
        unsigned pn = (unsigned)__hip_atomic_fetch_add(&base[n], 1,
                        __ATOMIC_RELAXED, __HIP_MEMORY_SCOPE_WORKGROUP);
        unsigned pe = (unsigned)__hip_atomic_fetch_add(&base[N_NODES + e], 1,
                        __ATOMIC_RELAXED, __HIP_MEMORY_SCOPE_WORKGROUP);
        ranks[m] = (xcc << 26) | (pn << 13) | pe;   // pn,pe < 8192 guaranteed
    }
}

// Per-key prefix over the 8 replica counts -> rb[k][key]; totals -> tot[key].
__global__ void replprefix_kernel(const int* __restrict__ cnt8,
                                  int* __restrict__ rb, int* __restrict__ tot) {
    int key = blockIdx.x * 256 + threadIdx.x;
    if (key < N_KEYS) {
        int base = 0;
#pragma unroll
        for (int k = 0; k < KREP; k++) {
            rb[k * N_KEYS + key] = base;
            base += cnt8[k * N_KEYS + key];
        }
        tot[key] = base;
    }
}

// Scan stage 1: per-tile (4096 elements) sums over the contiguous totals array.
__global__ void scan_partial_kernel(const int* __restrict__ cnt,
                                    int* __restrict__ pn, int* __restrict__ pe) {
    __shared__ int lds[16];
    int b = blockIdx.x;
    const int* src; int nElem; int tile; int* dst;
    if (b < N_TILES_N) { src = cnt;            nElem = N_NODES; tile = b;             dst = pn; }
    else               { src = cnt + N_NODES;  nElem = N_EDGES; tile = b - N_TILES_N; dst = pe; }
    int t = threadIdx.x;
    int i4 = tile * 1024 + t;
    int sum = 0;
    if (i4 * 4 < nElem) {
        int4 v = ((const int4*)src)[i4];
        sum = v.x + v.y + v.z + v.w;
    }
    for (int off = 1; off < 64; off <<= 1) sum += __shfl_xor(sum, off, 64);
    if ((t & 63) == 0) lds[t >> 6] = sum;
    __syncthreads();
    if (t < 16) {
        int s = lds[t];
        for (int off = 1; off < 16; off <<= 1) s += __shfl_xor(s, off, 64);
        if (t == 0) dst[tile] = s;
    }
}

// Scan stage 2: exclusive scan of tile sums; writes sentinel offsets.
__global__ void scan_base_kernel(const int* __restrict__ pn, const int* __restrict__ pe,
                                 int* __restrict__ bn, int* __restrict__ be,
                                 int* __restrict__ noff, int* __restrict__ eoff) {
    int w = threadIdx.x >> 6;
    int lane = threadIdx.x & 63;
    if (w == 0) {
        int v = (lane < N_TILES_N) ? pn[lane] : 0;
        int incl = v;
        for (int d = 1; d < 64; d <<= 1) { int u = __shfl_up(incl, d, 64); if (lane >= d) incl += u; }
        if (lane < N_TILES_N) bn[lane] = incl - v;
        if (lane == N_TILES_N - 1) noff[N_NODES] = incl;
    } else {
        int v = (lane < N_TILES_E) ? pe[lane] : 0;
        int incl = v;
        for (int d = 1; d < 64; d <<= 1) { int u = __shfl_up(incl, d, 64); if (lane >= d) incl += u; }
        if (lane < N_TILES_E) be[lane] = incl - v;
        if (lane == N_TILES_E - 1) eoff[N_EDGES] = incl;
    }
}

// Scan stage 3: block-level exclusive scan of each tile + tile base, int4 I/O.
__global__ void scan_write_kernel(const int* __restrict__ cnt,
                                  const int* __restrict__ bn, const int* __restrict__ be,
                                  int* __restrict__ noff, int* __restrict__ eoff) {
    __shared__ int wsum[16];
    int b = blockIdx.x;
    const int* src; int* dst; int nElem; int tile; int tbase;
    if (b < N_TILES_N) { src = cnt;           dst = noff; nElem = N_NODES; tile = b;             tbase = bn[tile]; }
    else               { src = cnt + N_NODES; dst = eoff; nElem = N_EDGES; tile = b - N_TILES_N; tbase = be[tile]; }
    int t = threadIdx.x;
    int lane = t & 63, w = t >> 6;
    int i4 = tile * 1024 + t;
    int4 c = make_int4(0, 0, 0, 0);
    bool valid = (i4 * 4 < nElem);
    if (valid) c = ((const int4*)src)[i4];
    int tsum = c.x + c.y + c.z + c.w;
    int incl = tsum;
    for (int d = 1; d < 64; d <<= 1) { int u = __shfl_up(incl, d, 64); if (lane >= d) incl += u; }
    if (lane == 63) wsum[w] = incl;
    __syncthreads();
    if (t < 16) {
        int v = wsum[t];
        int wi = v;
        for (int d = 1; d < 16; d <<= 1) { int u = __shfl_up(wi, d, 64); if (t >= d) wi += u; }
        wsum[t] = wi - v;
    }
    __syncthreads();
    int ex = tbase + wsum[w] + incl - tsum;
    if (valid) {
        int4 o;
        o.x = ex; o.y = ex + c.x; o.z = o.y + c.y; o.w = o.z + c.z;
        ((int4*)dst)[i4] = o;
    }
}

// Fill: atomic-free scatter. Global slot = seg_off + replica_base + subrank.
__global__ void fill_kernel(const int* __restrict__ node_idx,
                            const int* __restrict__ edge_idx,
                            const unsigned int* __restrict__ ranks,
                            const int* __restrict__ rb,
                            const int* __restrict__ noff, const int* __restrict__ eoff,
                            int* __restrict__ node_csr, int* __restrict__ edge_csr) {
    int m = blockIdx.x * 256 + threadIdx.x;
    if (m < M_INC) {
        int n = node_idx[m], e = edge_idx[m];
        unsigned rp = ranks[m];
        const int* rbk = rb + (rp >> 26) * N_KEYS;
        edge_csr[eoff[e] + rbk[N_NODES + e] + (int)(rp & 0x1fffu)] = n;
        node_csr[noff[n] + rbk[n] + (int)((rp >> 13) & 0x1fffu)] = e;
    }
}

// Stage 1: one wave per edge; 4 member-groups x 16 lanes, float4 per lane.
__global__ void stage1_kernel(const int* __restrict__ eoff, const int* __restrict__ ecsr,
                              const float* __restrict__ x, float* __restrict__ ef) {
    int wid = (blockIdx.x * 256 + threadIdx.x) >> 6;
    if (wid >= N_EDGES) return;
    int lane = threadIdx.x & 63;
    int group = lane >> 4;
    int gl = lane & 15;
    int s = eoff[wid], t = eoff[wid + 1];
    float4 acc = make_float4(0.f, 0.f, 0.f, 0.f);
    for (int base = s; base < t; base += 64) {
        int idx_l = (base + lane < t) ? ecsr[base + lane] : 0;
        int cnt = t - base; if (cnt > 64) cnt = 64;
        int steps = (cnt + 3) >> 2;
        for (int j = 0; j < steps; j++) {
            int p = 4 * j + group;
            int mi = __shfl(idx_l, p, 64);
            if (p < cnt) {
                float4 v = ((const float4*)x)[(size_t)mi * 16 + gl];
                acc.x += v.x; acc.y += v.y; acc.z += v.z; acc.w += v.w;
            }
        }
    }
    for (int off = 16; off < 64; off <<= 1) {
        acc.x += __shfl_xor(acc.x, off, 64);
        acc.y += __shfl_xor(acc.y, off, 64);
        acc.z += __shfl_xor(acc.z, off, 64);
        acc.w += __shfl_xor(acc.w, off, 64);
    }
    if (group == 0) {
        int card = t - s;
        float ber = (card > 0) ? (1.0f / (float)card) : 0.f;
        ((float4*)ef)[(size_t)wid * 16 + gl] =
            make_float4(acc.x * ber, acc.y * ber, acc.z * ber, acc.w * ber);
    }
}

// Stage 2: one wave per node; Dn computed inline from ew gathers.
__global__ void stage2_kernel(const int* __restrict__ noff, const int* __restrict__ ncsr,
                              const float* __restrict__ ef, const float* __restrict__ ew,
                              const float* __restrict__ x, float* __restrict__ out) {
    int wid = (blockIdx.x * 256 + threadIdx.x) >> 6;
    if (wid >= N_NODES) return;
    int lane = threadIdx.x & 63;
    int group = lane >> 4;
    int gl = lane & 15;
    int s = noff[wid], t = noff[wid + 1];
    float4 acc = make_float4(0.f, 0.f, 0.f, 0.f);
    float dn = 0.f;
    for (int base = s; base < t; base += 64) {
        bool lv = (base + lane < t);
        int idx_l = lv ? ncsr[base + lane] : 0;
        if (lv) dn += ew[idx_l];
        int cnt = t - base; if (cnt > 64) cnt = 64;
        int steps = (cnt + 3) >> 2;
        for (int j = 0; j < steps; j++) {
            int p = 4 * j + group;
            int mi = __shfl(idx_l, p, 64);
            if (p < cnt) {
                float4 v = ((const float4*)ef)[(size_t)mi * 16 + gl];
                acc.x += v.x; acc.y += v.y; acc.z += v.z; acc.w += v.w;
            }
        }
    }
    for (int off = 1; off < 64; off <<= 1) dn += __shfl_xor(dn, off, 64);
    for (int off = 16; off < 64; off <<= 1) {
        acc.x += __shfl_xor(acc.x, off, 64);
        acc.y += __shfl_xor(acc.y, off, 64);
        acc.z += __shfl_xor(acc.z, off, 64);
        acc.w += __shfl_xor(acc.w, off, 64);
    }
    if (group == 0) {
        float dnr = (dn > 0.f) ? (1.0f / dn) : 0.f;
        float4 xv = ((const float4*)x)[(size_t)wid * 16 + gl];
        float4 r;
        r.x = 0.5f * (xv.x + dnr * acc.x);
        r.y = 0.5f * (xv.y + dnr * acc.y);
        r.z = 0.5f * (xv.z + dnr * acc.z);
        r.w = 0.5f * (xv.w + dnr * acc.w);
        ((float4*)out)[(size_t)wid * 16 + gl] = r;
    }
}

extern "C" void kernel_launch(void* const* d_in, const int* in_sizes, int n_in,
                              void* d_out, int out_size, void* d_ws, size_t ws_size,
                              hipStream_t stream) {
    const float* x        = (const float*)d_in[0];
    const int*   node_idx = (const int*)d_in[1];
    const int*   edge_idx = (const int*)d_in[2];
    const float* ew       = (const float*)d_in[3];
    float* out = (float*)d_out;

    char* ws = (char*)d_ws;
    unsigned int* ranks    = (unsigned int*)(ws + 0);
    int*          noff     = (int*)(ws + 6400000);
    int*          eoff     = (int*)(ws + 6800016);
    int*          node_csr = (int*)(ws + 7000032);
    int*          edge_csr = (int*)(ws + 13400032);
    float*        ef       = (float*)(ws + 19800032);
    // lifetime-overlapped scratch:
    int* cnt8 = (int*)(ws + 7000032);    // 4.8MB under node_csr; dead before fill
    int* tot  = (int*)(ws + 13400032);   // 600KB under edge_csr; dead before fill
    int* rb   = (int*)(ws + 19800032);   // 4.8MB under ef; dead before stage1
    int* pn   = (int*)(ws + 24800032);   // scan scratch under ef; dead before stage1
    int* pe   = pn + 32;
    int* bn   = pn + 64;
    int* be   = pn + 96;

    hipMemsetAsync(cnt8, 0, (size_t)KREP * N_KEYS * 4, stream);

    passA_kernel<<<(M_INC + 255) / 256, 256, 0, stream>>>(node_idx, edge_idx, cnt8, ranks);
    replprefix_kernel<<<(N_KEYS + 255) / 256, 256, 0, stream>>>(cnt8, rb, tot);
    scan_partial_kernel<<<N_TILES_N + N_TILES_E, 1024, 0, stream>>>(tot, pn, pe);
    scan_base_kernel<<<1, 128, 0, stream>>>(pn, pe, bn, be, noff, eoff);
    scan_write_kernel<<<N_TILES_N + N_TILES_E, 1024, 0, stream>>>(tot, bn, be, noff, eoff);
    fill_kernel<<<(M_INC + 255) / 256, 256, 0, stream>>>(node_idx, edge_idx, ranks, rb,
                                                         noff, eoff, node_csr, edge_csr);
    stage1_kernel<<<(N_EDGES * 64 + 255) / 256, 256, 0, stream>>>(eoff, edge_csr, x, ef);
    stage2_kernel<<<(N_NODES * 64 + 255) / 256, 256, 0, stream>>>(noff, node_csr, ef, ew, x, out);
}

// Round 7
// 319.290 us; speedup vs baseline: 1.3038x; 1.2134x over previous
//
#include <hip/hip_runtime.h>

#define N_NODES 100000
#define N_EDGES 50000
#define N_KEYS  150000   // node keys [0,100000) then edge keys [100000,150000)
#define M_INC   1600000
#define D_HID   64

#define SUBR    16       // incidence subranges
#define SUBLEN  100000   // M_INC / SUBR
#define KPART   8192     // keys per LDS partition (32 KB histogram)
#define PN      13       // ceil(100000/8192)
#define PE      7        // ceil(50000/8192)

#define N_TILES_N 25   // ceil(100000/4096)
#define N_TILES_E 13   // ceil(50000/4096)

// ---- workspace layout (byte offsets, lifetime-overlapped) ----
// rank_n   [1.6M u16]   @ 0
// rank_e   [1.6M u16]   @ 3200000
// noff     [100001 int] @ 6400000
// eoff     [ 50001 int] @ 6800016
// node_csr [1.6M int]   @ 7000032    \  cnt_g [16x150K int, 9.6MB] overlaps
// edge_csr [1.6M int]   @ 13400032   /  here; dead before fill writes csr
// ef       [3.2M float] @ 19800032      rb [9.6MB] overlaps @ +0, scan scratch
//                                       @ +9600000; both dead before stage1

// Counting without global atomics: block (p,s) filters subrange s for keys in
// partition p, LDS-atomicAdd gives the subrank (stored u16), then dumps its
// 8192-bin histogram to cnt_g[s][key]. 320 blocks, zero device-scope atomics.
__global__ __launch_bounds__(256) void count_kernel(
        const int* __restrict__ node_idx, const int* __restrict__ edge_idx,
        unsigned short* __restrict__ rank_n, unsigned short* __restrict__ rank_e,
        int* __restrict__ cnt_g) {
    __shared__ unsigned int h[KPART];
    int bid = blockIdx.x;
    const int* idx; unsigned short* rk; int p, s, klim, goff;
    if (bid < PN * SUBR) {
        p = bid / SUBR; s = bid % SUBR;
        idx = node_idx; rk = rank_n; klim = N_NODES; goff = 0;
    } else {
        int b2 = bid - PN * SUBR;
        p = b2 / SUBR; s = b2 % SUBR;
        idx = edge_idx; rk = rank_e; klim = N_EDGES; goff = N_NODES;
    }
    int kbase = p * KPART;
    int t = threadIdx.x;
    for (int i = t; i < KPART; i += 256) h[i] = 0;
    __syncthreads();
    int mbase = s * SUBLEN;
    const int4* src4 = (const int4*)(idx + mbase);
    for (int i = t; i < SUBLEN / 4; i += 256) {
        int4 v = src4[i];
        int m0 = mbase + i * 4;
        int k;
        k = v.x - kbase; if ((unsigned)k < KPART) rk[m0 + 0] = (unsigned short)atomicAdd(&h[k], 1u);
        k = v.y - kbase; if ((unsigned)k < KPART) rk[m0 + 1] = (unsigned short)atomicAdd(&h[k], 1u);
        k = v.z - kbase; if ((unsigned)k < KPART) rk[m0 + 2] = (unsigned short)atomicAdd(&h[k], 1u);
        k = v.w - kbase; if ((unsigned)k < KPART) rk[m0 + 3] = (unsigned short)atomicAdd(&h[k], 1u);
    }
    __syncthreads();
    for (int i = t; i < KPART; i += 256) {
        int key = kbase + i;
        if (key < klim) cnt_g[s * N_KEYS + goff + key] = (int)h[i];
    }
}

// Per-key prefix over the 16 subrange counts -> rb[s][key]; totals -> tot[key].
__global__ void replprefix_kernel(const int* __restrict__ cnt_g,
                                  int* __restrict__ rb, int* __restrict__ tot) {
    int key = blockIdx.x * 256 + threadIdx.x;
    if (key < N_KEYS) {
        int base = 0;
#pragma unroll
        for (int k = 0; k < SUBR; k++) {
            rb[k * N_KEYS + key] = base;
            base += cnt_g[k * N_KEYS + key];
        }
        tot[key] = base;
    }
}

// Scan stage 1: per-tile (4096 elements) sums over the contiguous totals array.
__global__ void scan_partial_kernel(const int* __restrict__ cnt,
                                    int* __restrict__ pn, int* __restrict__ pe) {
    __shared__ int lds[16];
    int b = blockIdx.x;
    const int* src; int nElem; int tile; int* dst;
    if (b < N_TILES_N) { src = cnt;            nElem = N_NODES; tile = b;             dst = pn; }
    else               { src = cnt + N_NODES;  nElem = N_EDGES; tile = b - N_TILES_N; dst = pe; }
    int t = threadIdx.x;
    int i4 = tile * 1024 + t;
    int sum = 0;
    if (i4 * 4 < nElem) {
        int4 v = ((const int4*)src)[i4];
        sum = v.x + v.y + v.z + v.w;
    }
    for (int off = 1; off < 64; off <<= 1) sum += __shfl_xor(sum, off, 64);
    if ((t & 63) == 0) lds[t >> 6] = sum;
    __syncthreads();
    if (t < 16) {
        int s = lds[t];
        for (int off = 1; off < 16; off <<= 1) s += __shfl_xor(s, off, 64);
        if (t == 0) dst[tile] = s;
    }
}

// Scan stage 2: exclusive scan of tile sums; writes sentinel offsets.
__global__ void scan_base_kernel(const int* __restrict__ pn, const int* __restrict__ pe,
                                 int* __restrict__ bn, int* __restrict__ be,
                                 int* __restrict__ noff, int* __restrict__ eoff) {
    int w = threadIdx.x >> 6;
    int lane = threadIdx.x & 63;
    if (w == 0) {
        int v = (lane < N_TILES_N) ? pn[lane] : 0;
        int incl = v;
        for (int d = 1; d < 64; d <<= 1) { int u = __shfl_up(incl, d, 64); if (lane >= d) incl += u; }
        if (lane < N_TILES_N) bn[lane] = incl - v;
        if (lane == N_TILES_N - 1) noff[N_NODES] = incl;
    } else {
        int v = (lane < N_TILES_E) ? pe[lane] : 0;
        int incl = v;
        for (int d = 1; d < 64; d <<= 1) { int u = __shfl_up(incl, d, 64); if (lane >= d) incl += u; }
        if (lane < N_TILES_E) be[lane] = incl - v;
        if (lane == N_TILES_E - 1) eoff[N_EDGES] = incl;
    }
}

// Scan stage 3: block-level exclusive scan of each tile + tile base, int4 I/O.
__global__ void scan_write_kernel(const int* __restrict__ cnt,
                                  const int* __restrict__ bn, const int* __restrict__ be,
                                  int* __restrict__ noff, int* __restrict__ eoff) {
    __shared__ int wsum[16];
    int b = blockIdx.x;
    const int* src; int* dst; int nElem; int tile; int tbase;
    if (b < N_TILES_N) { src = cnt;           dst = noff; nElem = N_NODES; tile = b;             tbase = bn[tile]; }
    else               { src = cnt + N_NODES; dst = eoff; nElem = N_EDGES; tile = b - N_TILES_N; tbase = be[tile]; }
    int t = threadIdx.x;
    int lane = t & 63, w = t >> 6;
    int i4 = tile * 1024 + t;
    int4 c = make_int4(0, 0, 0, 0);
    bool valid = (i4 * 4 < nElem);
    if (valid) c = ((const int4*)src)[i4];
    int tsum = c.x + c.y + c.z + c.w;
    int incl = tsum;
    for (int d = 1; d < 64; d <<= 1) { int u = __shfl_up(incl, d, 64); if (lane >= d) incl += u; }
    if (lane == 63) wsum[w] = incl;
    __syncthreads();
    if (t < 16) {
        int v = wsum[t];
        int wi = v;
        for (int d = 1; d < 16; d <<= 1) { int u = __shfl_up(wi, d, 64); if (t >= d) wi += u; }
        wsum[t] = wi - v;
    }
    __syncthreads();
    int ex = tbase + wsum[w] + incl - tsum;
    if (valid) {
        int4 o;
        o.x = ex; o.y = ex + c.x; o.z = o.y + c.y; o.w = o.z + c.z;
        ((int4*)dst)[i4] = o;
    }
}

// Fill: atomic-free scatter. Slot = seg_off + subrange_base + subrank.
__global__ void fill_kernel(const int* __restrict__ node_idx,
                            const int* __restrict__ edge_idx,
                            const unsigned short* __restrict__ rank_n,
                            const unsigned short* __restrict__ rank_e,
                            const int* __restrict__ rb,
                            const int* __restrict__ noff, const int* __restrict__ eoff,
                            int* __restrict__ node_csr, int* __restrict__ edge_csr) {
    int m = blockIdx.x * 256 + threadIdx.x;
    if (m < M_INC) {
        int s = m / SUBLEN;
        const int* rbs = rb + s * N_KEYS;
        int n = node_idx[m], e = edge_idx[m];
        node_csr[noff[n] + rbs[n] + (int)rank_n[m]] = e;
        edge_csr[eoff[e] + rbs[N_NODES + e] + (int)rank_e[m]] = n;
    }
}

// Stage 1: one wave per edge; 4 member-groups x 16 lanes, float4 per lane.
__global__ void stage1_kernel(const int* __restrict__ eoff, const int* __restrict__ ecsr,
                              const float* __restrict__ x, float* __restrict__ ef) {
    int wid = (blockIdx.x * 256 + threadIdx.x) >> 6;
    if (wid >= N_EDGES) return;
    int lane = threadIdx.x & 63;
    int group = lane >> 4;
    int gl = lane & 15;
    int s = eoff[wid], t = eoff[wid + 1];
    float4 acc = make_float4(0.f, 0.f, 0.f, 0.f);
    for (int base = s; base < t; base += 64) {
        int idx_l = (base + lane < t) ? ecsr[base + lane] : 0;
        int cnt = t - base; if (cnt > 64) cnt = 64;
        int steps = (cnt + 3) >> 2;
        for (int j = 0; j < steps; j++) {
            int p = 4 * j + group;
            int mi = __shfl(idx_l, p, 64);
            if (p < cnt) {
                float4 v = ((const float4*)x)[(size_t)mi * 16 + gl];
                acc.x += v.x; acc.y += v.y; acc.z += v.z; acc.w += v.w;
            }
        }
    }
    for (int off = 16; off < 64; off <<= 1) {
        acc.x += __shfl_xor(acc.x, off, 64);
        acc.y += __shfl_xor(acc.y, off, 64);
        acc.z += __shfl_xor(acc.z, off, 64);
        acc.w += __shfl_xor(acc.w, off, 64);
    }
    if (group == 0) {
        int card = t - s;
        float ber = (card > 0) ? (1.0f / (float)card) : 0.f;
        ((float4*)ef)[(size_t)wid * 16 + gl] =
            make_float4(acc.x * ber, acc.y * ber, acc.z * ber, acc.w * ber);
    }
}

// Stage 2: one wave per node; Dn computed inline from ew gathers.
__global__ void stage2_kernel(const int* __restrict__ noff, const int* __restrict__ ncsr,
                              const float* __restrict__ ef, const float* __restrict__ ew,
                              const float* __restrict__ x, float* __restrict__ out) {
    int wid = (blockIdx.x * 256 + threadIdx.x) >> 6;
    if (wid >= N_NODES) return;
    int lane = threadIdx.x & 63;
    int group = lane >> 4;
    int gl = lane & 15;
    int s = noff[wid], t = noff[wid + 1];
    float4 acc = make_float4(0.f, 0.f, 0.f, 0.f);
    float dn = 0.f;
    for (int base = s; base < t; base += 64) {
        bool lv = (base + lane < t);
        int idx_l = lv ? ncsr[base + lane] : 0;
        if (lv) dn += ew[idx_l];
        int cnt = t - base; if (cnt > 64) cnt = 64;
        int steps = (cnt + 3) >> 2;
        for (int j = 0; j < steps; j++) {
            int p = 4 * j + group;
            int mi = __shfl(idx_l, p, 64);
            if (p < cnt) {
                float4 v = ((const float4*)ef)[(size_t)mi * 16 + gl];
                acc.x += v.x; acc.y += v.y; acc.z += v.z; acc.w += v.w;
            }
        }
    }
    for (int off = 1; off < 64; off <<= 1) dn += __shfl_xor(dn, off, 64);
    for (int off = 16; off < 64; off <<= 1) {
        acc.x += __shfl_xor(acc.x, off, 64);
        acc.y += __shfl_xor(acc.y, off, 64);
        acc.z += __shfl_xor(acc.z, off, 64);
        acc.w += __shfl_xor(acc.w, off, 64);
    }
    if (group == 0) {
        float dnr = (dn > 0.f) ? (1.0f / dn) : 0.f;
        float4 xv = ((const float4*)x)[(size_t)wid * 16 + gl];
        float4 r;
        r.x = 0.5f * (xv.x + dnr * acc.x);
        r.y = 0.5f * (xv.y + dnr * acc.y);
        r.z = 0.5f * (xv.z + dnr * acc.z);
        r.w = 0.5f * (xv.w + dnr * acc.w);
        ((float4*)out)[(size_t)wid * 16 + gl] = r;
    }
}

extern "C" void kernel_launch(void* const* d_in, const int* in_sizes, int n_in,
                              void* d_out, int out_size, void* d_ws, size_t ws_size,
                              hipStream_t stream) {
    const float* x        = (const float*)d_in[0];
    const int*   node_idx = (const int*)d_in[1];
    const int*   edge_idx = (const int*)d_in[2];
    const float* ew       = (const float*)d_in[3];
    float* out = (float*)d_out;

    char* ws = (char*)d_ws;
    unsigned short* rank_n   = (unsigned short*)(ws + 0);
    unsigned short* rank_e   = (unsigned short*)(ws + 3200000);
    int*            noff     = (int*)(ws + 6400000);
    int*            eoff     = (int*)(ws + 6800016);
    int*            node_csr = (int*)(ws + 7000032);
    int*            edge_csr = (int*)(ws + 13400032);
    float*          ef       = (float*)(ws + 19800032);
    // lifetime-overlapped scratch:
    int* cnt_g = (int*)(ws + 7000032);    // 9.6MB under node_csr+edge_csr; dead before fill
    int* rb    = (int*)(ws + 19800032);   // 9.6MB under ef; dead before stage1
    int* pn    = (int*)(ws + 29400032);   // scan scratch under ef tail; dead before stage1
    int* pe    = pn + 32;
    int* bn    = pn + 64;
    int* be    = pn + 96;
    int* tot   = pn + 256;                // hmm—needs 600KB; place after scan scratch
    tot = (int*)(ws + 29400032 + 4096);   // 600KB, still within ef tail (ends 32600032)

    count_kernel<<<(PN + PE) * SUBR, 256, 0, stream>>>(node_idx, edge_idx, rank_n, rank_e, cnt_g);
    replprefix_kernel<<<(N_KEYS + 255) / 256, 256, 0, stream>>>(cnt_g, rb, tot);
    scan_partial_kernel<<<N_TILES_N + N_TILES_E, 1024, 0, stream>>>(tot, pn, pe);
    scan_base_kernel<<<1, 128, 0, stream>>>(pn, pe, bn, be, noff, eoff);
    scan_write_kernel<<<N_TILES_N + N_TILES_E, 1024, 0, stream>>>(tot, bn, be, noff, eoff);
    fill_kernel<<<(M_INC + 255) / 256, 256, 0, stream>>>(node_idx, edge_idx, rank_n, rank_e,
                                                         rb, noff, eoff, node_csr, edge_csr);
    stage1_kernel<<<(N_EDGES * 64 + 255) / 256, 256, 0, stream>>>(eoff, edge_csr, x, ef);
    stage2_kernel<<<(N_NODES * 64 + 255) / 256, 256, 0, stream>>>(noff, node_csr, ef, ew, x, out);
}

// Round 8
// 294.089 us; speedup vs baseline: 1.4155x; 1.0857x over previous
//
#include <hip/hip_runtime.h>

#define N_NODES 100000
#define N_EDGES 50000
#define N_KEYS  150000   // node keys [0,100000) then edge keys [100000,150000)
#define M_INC   1600000
#define D_HID   64

#define SUBR    16       // incidence subranges
#define SUBLEN  100000   // M_INC / SUBR
#define KPART   8192     // keys per LDS partition (32 KB histogram)
#define PN      13       // ceil(100000/8192)
#define PE      7        // ceil(50000/8192)

#define N_TILES_N 25   // ceil(100000/4096)
#define N_TILES_E 13   // ceil(50000/4096)

// ---- workspace layout (byte offsets, lifetime-overlapped) ----
// rank_n [1.6M u16] @0, rank_e @3200000          -- dead after fill
// ef bf16 [3.2M]    @0  (6.4MB)                  -- written by stage1 (post-fill)
// noff [100001 int] @6400000 ; eoff @6800016
// node_csr @7000032, edge_csr @13400032          -- cnt_g overlaps (dead after replprefix)
// rb [9.6MB] @19800032 + scan scratch @29400032  -- dead after fill
// xh bf16 [6.4M] @19800032 (12.8MB)              -- written by cvt AFTER fill

__device__ __forceinline__ unsigned pack2bf(float a, float b) {
    unsigned ua = __float_as_uint(a); ua = (ua + 0x7fffu + ((ua >> 16) & 1u)) >> 16;
    unsigned ub = __float_as_uint(b); ub = (ub + 0x7fffu + ((ub >> 16) & 1u)) >> 16;
    return ua | (ub << 16);
}

// Counting without global atomics: block (p,s) filters subrange s for keys in
// partition p, LDS-atomicAdd gives the subrank (u16), then dumps its histogram.
__global__ __launch_bounds__(256) void count_kernel(
        const int* __restrict__ node_idx, const int* __restrict__ edge_idx,
        unsigned short* __restrict__ rank_n, unsigned short* __restrict__ rank_e,
        int* __restrict__ cnt_g) {
    __shared__ unsigned int h[KPART];
    int bid = blockIdx.x;
    const int* idx; unsigned short* rk; int p, s, klim, goff;
    if (bid < PN * SUBR) {
        p = bid / SUBR; s = bid % SUBR;
        idx = node_idx; rk = rank_n; klim = N_NODES; goff = 0;
    } else {
        int b2 = bid - PN * SUBR;
        p = b2 / SUBR; s = b2 % SUBR;
        idx = edge_idx; rk = rank_e; klim = N_EDGES; goff = N_NODES;
    }
    int kbase = p * KPART;
    int t = threadIdx.x;
    for (int i = t; i < KPART; i += 256) h[i] = 0;
    __syncthreads();
    int mbase = s * SUBLEN;
    const int4* src4 = (const int4*)(idx + mbase);
    for (int i = t; i < SUBLEN / 4; i += 256) {
        int4 v = src4[i];
        int m0 = mbase + i * 4;
        int k;
        k = v.x - kbase; if ((unsigned)k < KPART) rk[m0 + 0] = (unsigned short)atomicAdd(&h[k], 1u);
        k = v.y - kbase; if ((unsigned)k < KPART) rk[m0 + 1] = (unsigned short)atomicAdd(&h[k], 1u);
        k = v.z - kbase; if ((unsigned)k < KPART) rk[m0 + 2] = (unsigned short)atomicAdd(&h[k], 1u);
        k = v.w - kbase; if ((unsigned)k < KPART) rk[m0 + 3] = (unsigned short)atomicAdd(&h[k], 1u);
    }
    __syncthreads();
    for (int i = t; i < KPART; i += 256) {
        int key = kbase + i;
        if (key < klim) cnt_g[s * N_KEYS + goff + key] = (int)h[i];
    }
}

// Per-key prefix over the 16 subrange counts -> rb[s][key]; totals -> tot[key].
__global__ void replprefix_kernel(const int* __restrict__ cnt_g,
                                  int* __restrict__ rb, int* __restrict__ tot) {
    int key = blockIdx.x * 256 + threadIdx.x;
    if (key < N_KEYS) {
        int base = 0;
#pragma unroll
        for (int k = 0; k < SUBR; k++) {
            rb[k * N_KEYS + key] = base;
            base += cnt_g[k * N_KEYS + key];
        }
        tot[key] = base;
    }
}

// Scan stage 1: per-tile (4096 elements) sums over the contiguous totals array.
__global__ void scan_partial_kernel(const int* __restrict__ cnt,
                                    int* __restrict__ pn, int* __restrict__ pe) {
    __shared__ int lds[16];
    int b = blockIdx.x;
    const int* src; int nElem; int tile; int* dst;
    if (b < N_TILES_N) { src = cnt;            nElem = N_NODES; tile = b;             dst = pn; }
    else               { src = cnt + N_NODES;  nElem = N_EDGES; tile = b - N_TILES_N; dst = pe; }
    int t = threadIdx.x;
    int i4 = tile * 1024 + t;
    int sum = 0;
    if (i4 * 4 < nElem) {
        int4 v = ((const int4*)src)[i4];
        sum = v.x + v.y + v.z + v.w;
    }
    for (int off = 1; off < 64; off <<= 1) sum += __shfl_xor(sum, off, 64);
    if ((t & 63) == 0) lds[t >> 6] = sum;
    __syncthreads();
    if (t < 16) {
        int s = lds[t];
        for (int off = 1; off < 16; off <<= 1) s += __shfl_xor(s, off, 64);
        if (t == 0) dst[tile] = s;
    }
}

// Scan stage 2: exclusive scan of tile sums; writes sentinel offsets.
__global__ void scan_base_kernel(const int* __restrict__ pn, const int* __restrict__ pe,
                                 int* __restrict__ bn, int* __restrict__ be,
                                 int* __restrict__ noff, int* __restrict__ eoff) {
    int w = threadIdx.x >> 6;
    int lane = threadIdx.x & 63;
    if (w == 0) {
        int v = (lane < N_TILES_N) ? pn[lane] : 0;
        int incl = v;
        for (int d = 1; d < 64; d <<= 1) { int u = __shfl_up(incl, d, 64); if (lane >= d) incl += u; }
        if (lane < N_TILES_N) bn[lane] = incl - v;
        if (lane == N_TILES_N - 1) noff[N_NODES] = incl;
    } else {
        int v = (lane < N_TILES_E) ? pe[lane] : 0;
        int incl = v;
        for (int d = 1; d < 64; d <<= 1) { int u = __shfl_up(incl, d, 64); if (lane >= d) incl += u; }
        if (lane < N_TILES_E) be[lane] = incl - v;
        if (lane == N_TILES_E - 1) eoff[N_EDGES] = incl;
    }
}

// Scan stage 3: block-level exclusive scan of each tile + tile base, int4 I/O.
__global__ void scan_write_kernel(const int* __restrict__ cnt,
                                  const int* __restrict__ bn, const int* __restrict__ be,
                                  int* __restrict__ noff, int* __restrict__ eoff) {
    __shared__ int wsum[16];
    int b = blockIdx.x;
    const int* src; int* dst; int nElem; int tile; int tbase;
    if (b < N_TILES_N) { src = cnt;           dst = noff; nElem = N_NODES; tile = b;             tbase = bn[tile]; }
    else               { src = cnt + N_NODES; dst = eoff; nElem = N_EDGES; tile = b - N_TILES_N; tbase = be[tile]; }
    int t = threadIdx.x;
    int lane = t & 63, w = t >> 6;
    int i4 = tile * 1024 + t;
    int4 c = make_int4(0, 0, 0, 0);
    bool valid = (i4 * 4 < nElem);
    if (valid) c = ((const int4*)src)[i4];
    int tsum = c.x + c.y + c.z + c.w;
    int incl = tsum;
    for (int d = 1; d < 64; d <<= 1) { int u = __shfl_up(incl, d, 64); if (lane >= d) incl += u; }
    if (lane == 63) wsum[w] = incl;
    __syncthreads();
    if (t < 16) {
        int v = wsum[t];
        int wi = v;
        for (int d = 1; d < 16; d <<= 1) { int u = __shfl_up(wi, d, 64); if (t >= d) wi += u; }
        wsum[t] = wi - v;
    }
    __syncthreads();
    int ex = tbase + wsum[w] + incl - tsum;
    if (valid) {
        int4 o;
        o.x = ex; o.y = ex + c.x; o.z = o.y + c.y; o.w = o.z + c.z;
        ((int4*)dst)[i4] = o;
    }
}

// Fill: atomic-free scatter. Slot = seg_off + subrange_base + subrank.
__global__ void fill_kernel(const int* __restrict__ node_idx,
                            const int* __restrict__ edge_idx,
                            const unsigned short* __restrict__ rank_n,
                            const unsigned short* __restrict__ rank_e,
                            const int* __restrict__ rb,
                            const int* __restrict__ noff, const int* __restrict__ eoff,
                            int* __restrict__ node_csr, int* __restrict__ edge_csr) {
    int m = blockIdx.x * 256 + threadIdx.x;
    if (m < M_INC) {
        int s = m / SUBLEN;
        const int* rbs = rb + s * N_KEYS;
        int n = node_idx[m], e = edge_idx[m];
        node_csr[noff[n] + rbs[n] + (int)rank_n[m]] = e;
        edge_csr[eoff[e] + rbs[N_NODES + e] + (int)rank_e[m]] = n;
    }
}

// Convert x (fp32) -> xh (bf16, RNE). 8 elements / thread, coalesced.
__global__ void cvt_kernel(const float* __restrict__ x, unsigned int* __restrict__ xh) {
    int i = blockIdx.x * 256 + threadIdx.x;           // 8-element group
    if (i < (N_NODES * D_HID) / 8) {
        const float4* x4 = (const float4*)x;
        float4 a = x4[i * 2], b = x4[i * 2 + 1];
        uint4 o;
        o.x = pack2bf(a.x, a.y); o.y = pack2bf(a.z, a.w);
        o.z = pack2bf(b.x, b.y); o.w = pack2bf(b.z, b.w);
        ((uint4*)xh)[i] = o;
    }
}

// Stage 1: one wave per edge; 8 member-groups x 8 lanes, 16B (8 bf16) per lane.
__global__ void stage1_kernel(const int* __restrict__ eoff, const int* __restrict__ ecsr,
                              const uint4* __restrict__ xh, uint4* __restrict__ ef) {
    int wid = (blockIdx.x * 256 + threadIdx.x) >> 6;
    if (wid >= N_EDGES) return;
    int lane = threadIdx.x & 63;
    int group = lane >> 3;
    int gl = lane & 7;
    int s = eoff[wid], t = eoff[wid + 1];
    float acc[8] = {0.f, 0.f, 0.f, 0.f, 0.f, 0.f, 0.f, 0.f};
    for (int base = s; base < t; base += 64) {
        int idx_l = (base + lane < t) ? ecsr[base + lane] : 0;
        int cnt = t - base; if (cnt > 64) cnt = 64;
        int steps = (cnt + 7) >> 3;
        for (int j = 0; j < steps; j++) {
            int p = 8 * j + group;
            int mi = __shfl(idx_l, p, 64);
            if (p < cnt) {
                uint4 v = xh[(size_t)mi * 8 + gl];
                acc[0] += __uint_as_float(v.x << 16); acc[1] += __uint_as_float(v.x & 0xffff0000u);
                acc[2] += __uint_as_float(v.y << 16); acc[3] += __uint_as_float(v.y & 0xffff0000u);
                acc[4] += __uint_as_float(v.z << 16); acc[5] += __uint_as_float(v.z & 0xffff0000u);
                acc[6] += __uint_as_float(v.w << 16); acc[7] += __uint_as_float(v.w & 0xffff0000u);
            }
        }
    }
    for (int off = 8; off < 64; off <<= 1)
#pragma unroll
        for (int i = 0; i < 8; i++) acc[i] += __shfl_xor(acc[i], off, 64);
    if (group == 0) {
        int card = t - s;
        float ber = (card > 0) ? (1.0f / (float)card) : 0.f;
        uint4 o;
        o.x = pack2bf(acc[0] * ber, acc[1] * ber);
        o.y = pack2bf(acc[2] * ber, acc[3] * ber);
        o.z = pack2bf(acc[4] * ber, acc[5] * ber);
        o.w = pack2bf(acc[6] * ber, acc[7] * ber);
        ef[(size_t)wid * 8 + gl] = o;
    }
}

// Stage 2: one wave per node; bf16 ef gathers, fp32 residual + output.
__global__ void stage2_kernel(const int* __restrict__ noff, const int* __restrict__ ncsr,
                              const uint4* __restrict__ ef, const float* __restrict__ ew,
                              const float* __restrict__ x, float* __restrict__ out) {
    int wid = (blockIdx.x * 256 + threadIdx.x) >> 6;
    if (wid >= N_NODES) return;
    int lane = threadIdx.x & 63;
    int group = lane >> 3;
    int gl = lane & 7;
    int s = noff[wid], t = noff[wid + 1];
    float acc[8] = {0.f, 0.f, 0.f, 0.f, 0.f, 0.f, 0.f, 0.f};
    float dn = 0.f;
    for (int base = s; base < t; base += 64) {
        bool lv = (base + lane < t);
        int idx_l = lv ? ncsr[base + lane] : 0;
        if (lv) dn += ew[idx_l];
        int cnt = t - base; if (cnt > 64) cnt = 64;
        int steps = (cnt + 7) >> 3;
        for (int j = 0; j < steps; j++) {
            int p = 8 * j + group;
            int mi = __shfl(idx_l, p, 64);
            if (p < cnt) {
                uint4 v = ef[(size_t)mi * 8 + gl];
                acc[0] += __uint_as_float(v.x << 16); acc[1] += __uint_as_float(v.x & 0xffff0000u);
                acc[2] += __uint_as_float(v.y << 16); acc[3] += __uint_as_float(v.y & 0xffff0000u);
                acc[4] += __uint_as_float(v.z << 16); acc[5] += __uint_as_float(v.z & 0xffff0000u);
                acc[6] += __uint_as_float(v.w << 16); acc[7] += __uint_as_float(v.w & 0xffff0000u);
            }
        }
    }
    for (int off = 1; off < 64; off <<= 1) dn += __shfl_xor(dn, off, 64);
    for (int off = 8; off < 64; off <<= 1)
#pragma unroll
        for (int i = 0; i < 8; i++) acc[i] += __shfl_xor(acc[i], off, 64);
    if (group == 0) {
        float dnr = (dn > 0.f) ? (1.0f / dn) : 0.f;
        const float4* x4 = (const float4*)x;
        float4* o4 = (float4*)out;
        float4 a = x4[(size_t)wid * 16 + gl * 2];
        float4 b = x4[(size_t)wid * 16 + gl * 2 + 1];
        float4 ra, rb2;
        ra.x = 0.5f * (a.x + dnr * acc[0]);
        ra.y = 0.5f * (a.y + dnr * acc[1]);
        ra.z = 0.5f * (a.z + dnr * acc[2]);
        ra.w = 0.5f * (a.w + dnr * acc[3]);
        rb2.x = 0.5f * (b.x + dnr * acc[4]);
        rb2.y = 0.5f * (b.y + dnr * acc[5]);
        rb2.z = 0.5f * (b.z + dnr * acc[6]);
        rb2.w = 0.5f * (b.w + dnr * acc[7]);
        o4[(size_t)wid * 16 + gl * 2] = ra;
        o4[(size_t)wid * 16 + gl * 2 + 1] = rb2;
    }
}

extern "C" void kernel_launch(void* const* d_in, const int* in_sizes, int n_in,
                              void* d_out, int out_size, void* d_ws, size_t ws_size,
                              hipStream_t stream) {
    const float* x        = (const float*)d_in[0];
    const int*   node_idx = (const int*)d_in[1];
    const int*   edge_idx = (const int*)d_in[2];
    const float* ew       = (const float*)d_in[3];
    float* out = (float*)d_out;

    char* ws = (char*)d_ws;
    unsigned short* rank_n   = (unsigned short*)(ws + 0);
    unsigned short* rank_e   = (unsigned short*)(ws + 3200000);
    int*            noff     = (int*)(ws + 6400000);
    int*            eoff     = (int*)(ws + 6800016);
    int*            node_csr = (int*)(ws + 7000032);
    int*            edge_csr = (int*)(ws + 13400032);
    // lifetime-overlapped scratch:
    int*          cnt_g = (int*)(ws + 7000032);    // 9.6MB under csr; dead after replprefix
    int*          rb    = (int*)(ws + 19800032);   // 9.6MB; dead after fill
    int*          pn    = (int*)(ws + 29400032);   // scan scratch; dead after scan_write
    int*          pe    = pn + 32;
    int*          bn    = pn + 64;
    int*          be    = pn + 96;
    int*          tot   = (int*)(ws + 29404128);   // 600KB; dead after scan_write
    unsigned int* ef    = (unsigned int*)(ws + 0);        // bf16, written post-fill
    unsigned int* xh    = (unsigned int*)(ws + 19800032); // bf16, written post-fill

    count_kernel<<<(PN + PE) * SUBR, 256, 0, stream>>>(node_idx, edge_idx, rank_n, rank_e, cnt_g);
    replprefix_kernel<<<(N_KEYS + 255) / 256, 256, 0, stream>>>(cnt_g, rb, tot);
    scan_partial_kernel<<<N_TILES_N + N_TILES_E, 1024, 0, stream>>>(tot, pn, pe);
    scan_base_kernel<<<1, 128, 0, stream>>>(pn, pe, bn, be, noff, eoff);
    scan_write_kernel<<<N_TILES_N + N_TILES_E, 1024, 0, stream>>>(tot, bn, be, noff, eoff);
    fill_kernel<<<(M_INC + 255) / 256, 256, 0, stream>>>(node_idx, edge_idx, rank_n, rank_e,
                                                         rb, noff, eoff, node_csr, edge_csr);
    cvt_kernel<<<((N_NODES * D_HID / 8) + 255) / 256, 256, 0, stream>>>(x, xh);
    stage1_kernel<<<(N_EDGES * 64 + 255) / 256, 256, 0, stream>>>(eoff, edge_csr,
                                                                  (const uint4*)xh, (uint4*)ef);
    stage2_kernel<<<(N_NODES * 64 + 255) / 256, 256, 0, stream>>>(noff, node_csr,
                                                                  (const uint4*)ef, ew, x, out);
}

// Round 9
// 266.495 us; speedup vs baseline: 1.5621x; 1.1035x over previous
//
#include <hip/hip_runtime.h>

#define N_NODES 100000
#define N_EDGES 50000
#define N_KEYS  150000   // node keys [0,100000) then edge keys [100000,150000)
#define M_INC   1600000
#define D_HID   64

#define SUBR    32       // incidence subranges
#define SUBLEN  50000    // M_INC / SUBR
#define KPART   8192     // keys per LDS partition (32 KB histogram)
#define PN      13       // ceil(100000/8192)
#define PE      7        // ceil(50000/8192)

#define N_TILES_N 25   // ceil(100000/4096)
#define N_TILES_E 13   // ceil(50000/4096)

// ---- workspace layout (byte offsets, lifetime-overlapped) ----
// rank_n [1.6M u16] @0, rank_e @3200000            -- dead after fill
// ef bf16 [3.2M]    @0  (6.4MB)                    -- written by stage1 (post-fill)
// noff [100001 int] @6400000 ; eoff @6800016
// node_csr @7000032, edge_csr @13400032            -- cnt_g u16 [9.6MB] overlaps
//                                                     (dead after replprefix)
// rb u16 [9.6MB] @19800032, scan scratch @29400032 -- dead after fill / scan
// xh bf16 [6.4M] @19800032 (12.8MB)                -- written by cvt AFTER fill

__device__ __forceinline__ unsigned pack2bf(float a, float b) {
    unsigned ua = __float_as_uint(a); ua = (ua + 0x7fffu + ((ua >> 16) & 1u)) >> 16;
    unsigned ub = __float_as_uint(b); ub = (ub + 0x7fffu + ((ub >> 16) & 1u)) >> 16;
    return ua | (ub << 16);
}

// Counting without global atomics: block (p,s) filters subrange s for keys in
// partition p, LDS-atomicAdd gives the subrank (u16), then dumps its histogram.
// 1024 threads x 640 blocks: ~13 loop trips/thread, 32 waves/CU for latency hiding.
__global__ __launch_bounds__(1024) void count_kernel(
        const int* __restrict__ node_idx, const int* __restrict__ edge_idx,
        unsigned short* __restrict__ rank_n, unsigned short* __restrict__ rank_e,
        unsigned short* __restrict__ cnt_g) {
    __shared__ unsigned int h[KPART];
    int bid = blockIdx.x;
    const int* idx; unsigned short* rk; int p, s, klim, goff;
    if (bid < PN * SUBR) {
        p = bid / SUBR; s = bid % SUBR;
        idx = node_idx; rk = rank_n; klim = N_NODES; goff = 0;
    } else {
        int b2 = bid - PN * SUBR;
        p = b2 / SUBR; s = b2 % SUBR;
        idx = edge_idx; rk = rank_e; klim = N_EDGES; goff = N_NODES;
    }
    int kbase = p * KPART;
    int t = threadIdx.x;
    for (int i = t; i < KPART; i += 1024) h[i] = 0;
    __syncthreads();
    int mbase = s * SUBLEN;
    const int4* src4 = (const int4*)(idx + mbase);
    for (int i = t; i < SUBLEN / 4; i += 1024) {
        int4 v = src4[i];
        int m0 = mbase + i * 4;
        int k;
        k = v.x - kbase; if ((unsigned)k < KPART) rk[m0 + 0] = (unsigned short)atomicAdd(&h[k], 1u);
        k = v.y - kbase; if ((unsigned)k < KPART) rk[m0 + 1] = (unsigned short)atomicAdd(&h[k], 1u);
        k = v.z - kbase; if ((unsigned)k < KPART) rk[m0 + 2] = (unsigned short)atomicAdd(&h[k], 1u);
        k = v.w - kbase; if ((unsigned)k < KPART) rk[m0 + 3] = (unsigned short)atomicAdd(&h[k], 1u);
    }
    __syncthreads();
    for (int i = t; i < KPART; i += 1024) {
        int key = kbase + i;
        if (key < klim) cnt_g[s * N_KEYS + goff + key] = (unsigned short)h[i];
    }
}

// Per-key prefix over the 32 subrange counts -> rb[s][key] (u16); totals -> tot[key].
__global__ void replprefix_kernel(const unsigned short* __restrict__ cnt_g,
                                  unsigned short* __restrict__ rb, int* __restrict__ tot) {
    int key = blockIdx.x * 256 + threadIdx.x;
    if (key < N_KEYS) {
        int base = 0;
#pragma unroll
        for (int k = 0; k < SUBR; k++) {
            rb[k * N_KEYS + key] = (unsigned short)base;
            base += (int)cnt_g[k * N_KEYS + key];
        }
        tot[key] = base;
    }
}

// Scan stage 1: per-tile (4096 elements) sums over the contiguous totals array.
__global__ void scan_partial_kernel(const int* __restrict__ cnt,
                                    int* __restrict__ pn, int* __restrict__ pe) {
    __shared__ int lds[16];
    int b = blockIdx.x;
    const int* src; int nElem; int tile; int* dst;
    if (b < N_TILES_N) { src = cnt;            nElem = N_NODES; tile = b;             dst = pn; }
    else               { src = cnt + N_NODES;  nElem = N_EDGES; tile = b - N_TILES_N; dst = pe; }
    int t = threadIdx.x;
    int i4 = tile * 1024 + t;
    int sum = 0;
    if (i4 * 4 < nElem) {
        int4 v = ((const int4*)src)[i4];
        sum = v.x + v.y + v.z + v.w;
    }
    for (int off = 1; off < 64; off <<= 1) sum += __shfl_xor(sum, off, 64);
    if ((t & 63) == 0) lds[t >> 6] = sum;
    __syncthreads();
    if (t < 16) {
        int s = lds[t];
        for (int off = 1; off < 16; off <<= 1) s += __shfl_xor(s, off, 64);
        if (t == 0) dst[tile] = s;
    }
}

// Scan stage 2: exclusive scan of tile sums; writes sentinel offsets.
__global__ void scan_base_kernel(const int* __restrict__ pn, const int* __restrict__ pe,
                                 int* __restrict__ bn, int* __restrict__ be,
                                 int* __restrict__ noff, int* __restrict__ eoff) {
    int w = threadIdx.x >> 6;
    int lane = threadIdx.x & 63;
    if (w == 0) {
        int v = (lane < N_TILES_N) ? pn[lane] : 0;
        int incl = v;
        for (int d = 1; d < 64; d <<= 1) { int u = __shfl_up(incl, d, 64); if (lane >= d) incl += u; }
        if (lane < N_TILES_N) bn[lane] = incl - v;
        if (lane == N_TILES_N - 1) noff[N_NODES] = incl;
    } else {
        int v = (lane < N_TILES_E) ? pe[lane] : 0;
        int incl = v;
        for (int d = 1; d < 64; d <<= 1) { int u = __shfl_up(incl, d, 64); if (lane >= d) incl += u; }
        if (lane < N_TILES_E) be[lane] = incl - v;
        if (lane == N_TILES_E - 1) eoff[N_EDGES] = incl;
    }
}

// Scan stage 3: block-level exclusive scan of each tile + tile base, int4 I/O.
__global__ void scan_write_kernel(const int* __restrict__ cnt,
                                  const int* __restrict__ bn, const int* __restrict__ be,
                                  int* __restrict__ noff, int* __restrict__ eoff) {
    __shared__ int wsum[16];
    int b = blockIdx.x;
    const int* src; int* dst; int nElem; int tile; int tbase;
    if (b < N_TILES_N) { src = cnt;           dst = noff; nElem = N_NODES; tile = b;             tbase = bn[tile]; }
    else               { src = cnt + N_NODES; dst = eoff; nElem = N_EDGES; tile = b - N_TILES_N; tbase = be[tile]; }
    int t = threadIdx.x;
    int lane = t & 63, w = t >> 6;
    int i4 = tile * 1024 + t;
    int4 c = make_int4(0, 0, 0, 0);
    bool valid = (i4 * 4 < nElem);
    if (valid) c = ((const int4*)src)[i4];
    int tsum = c.x + c.y + c.z + c.w;
    int incl = tsum;
    for (int d = 1; d < 64; d <<= 1) { int u = __shfl_up(incl, d, 64); if (lane >= d) incl += u; }
    if (lane == 63) wsum[w] = incl;
    __syncthreads();
    if (t < 16) {
        int v = wsum[t];
        int wi = v;
        for (int d = 1; d < 16; d <<= 1) { int u = __shfl_up(wi, d, 64); if (t >= d) wi += u; }
        wsum[t] = wi - v;
    }
    __syncthreads();
    int ex = tbase + wsum[w] + incl - tsum;
    if (valid) {
        int4 o;
        o.x = ex; o.y = ex + c.x; o.z = o.y + c.y; o.w = o.z + c.z;
        ((int4*)dst)[i4] = o;
    }
}

// Fill: atomic-free scatter. Slot = seg_off + subrange_base + subrank.
__global__ void fill_kernel(const int* __restrict__ node_idx,
                            const int* __restrict__ edge_idx,
                            const unsigned short* __restrict__ rank_n,
                            const unsigned short* __restrict__ rank_e,
                            const unsigned short* __restrict__ rb,
                            const int* __restrict__ noff, const int* __restrict__ eoff,
                            int* __restrict__ node_csr, int* __restrict__ edge_csr) {
    int m = blockIdx.x * 256 + threadIdx.x;
    if (m < M_INC) {
        int s = m / SUBLEN;
        const unsigned short* rbs = rb + s * N_KEYS;
        int n = node_idx[m], e = edge_idx[m];
        node_csr[noff[n] + (int)rbs[n] + (int)rank_n[m]] = e;
        edge_csr[eoff[e] + (int)rbs[N_NODES + e] + (int)rank_e[m]] = n;
    }
}

// Convert x (fp32) -> xh (bf16, RNE). 8 elements / thread, coalesced.
__global__ void cvt_kernel(const float* __restrict__ x, unsigned int* __restrict__ xh) {
    int i = blockIdx.x * 256 + threadIdx.x;           // 8-element group
    if (i < (N_NODES * D_HID) / 8) {
        const float4* x4 = (const float4*)x;
        float4 a = x4[i * 2], b = x4[i * 2 + 1];
        uint4 o;
        o.x = pack2bf(a.x, a.y); o.y = pack2bf(a.z, a.w);
        o.z = pack2bf(b.x, b.y); o.w = pack2bf(b.z, b.w);
        ((uint4*)xh)[i] = o;
    }
}

// Stage 1: one wave per edge; 8 member-groups x 8 lanes, 16B (8 bf16) per lane.
__global__ void stage1_kernel(const int* __restrict__ eoff, const int* __restrict__ ecsr,
                              const uint4* __restrict__ xh, uint4* __restrict__ ef) {
    int wid = (blockIdx.x * 256 + threadIdx.x) >> 6;
    if (wid >= N_EDGES) return;
    int lane = threadIdx.x & 63;
    int group = lane >> 3;
    int gl = lane & 7;
    int s = eoff[wid], t = eoff[wid + 1];
    float acc[8] = {0.f, 0.f, 0.f, 0.f, 0.f, 0.f, 0.f, 0.f};
    for (int base = s; base < t; base += 64) {
        int idx_l = (base + lane < t) ? ecsr[base + lane] : 0;
        int cnt = t - base; if (cnt > 64) cnt = 64;
        int steps = (cnt + 7) >> 3;
        for (int j = 0; j < steps; j++) {
            int p = 8 * j + group;
            int mi = __shfl(idx_l, p, 64);
            if (p < cnt) {
                uint4 v = xh[(size_t)mi * 8 + gl];
                acc[0] += __uint_as_float(v.x << 16); acc[1] += __uint_as_float(v.x & 0xffff0000u);
                acc[2] += __uint_as_float(v.y << 16); acc[3] += __uint_as_float(v.y & 0xffff0000u);
                acc[4] += __uint_as_float(v.z << 16); acc[5] += __uint_as_float(v.z & 0xffff0000u);
                acc[6] += __uint_as_float(v.w << 16); acc[7] += __uint_as_float(v.w & 0xffff0000u);
            }
        }
    }
    for (int off = 8; off < 64; off <<= 1)
#pragma unroll
        for (int i = 0; i < 8; i++) acc[i] += __shfl_xor(acc[i], off, 64);
    if (group == 0) {
        int card = t - s;
        float ber = (card > 0) ? (1.0f / (float)card) : 0.f;
        uint4 o;
        o.x = pack2bf(acc[0] * ber, acc[1] * ber);
        o.y = pack2bf(acc[2] * ber, acc[3] * ber);
        o.z = pack2bf(acc[4] * ber, acc[5] * ber);
        o.w = pack2bf(acc[6] * ber, acc[7] * ber);
        ef[(size_t)wid * 8 + gl] = o;
    }
}

// Stage 2: one wave per node; bf16 ef gathers, fp32 residual + output.
__global__ void stage2_kernel(const int* __restrict__ noff, const int* __restrict__ ncsr,
                              const uint4* __restrict__ ef, const float* __restrict__ ew,
                              const float* __restrict__ x, float* __restrict__ out) {
    int wid = (blockIdx.x * 256 + threadIdx.x) >> 6;
    if (wid >= N_NODES) return;
    int lane = threadIdx.x & 63;
    int group = lane >> 3;
    int gl = lane & 7;
    int s = noff[wid], t = noff[wid + 1];
    float acc[8] = {0.f, 0.f, 0.f, 0.f, 0.f, 0.f, 0.f, 0.f};
    float dn = 0.f;
    for (int base = s; base < t; base += 64) {
        bool lv = (base + lane < t);
        int idx_l = lv ? ncsr[base + lane] : 0;
        if (lv) dn += ew[idx_l];
        int cnt = t - base; if (cnt > 64) cnt = 64;
        int steps = (cnt + 7) >> 3;
        for (int j = 0; j < steps; j++) {
            int p = 8 * j + group;
            int mi = __shfl(idx_l, p, 64);
            if (p < cnt) {
                uint4 v = ef[(size_t)mi * 8 + gl];
                acc[0] += __uint_as_float(v.x << 16); acc[1] += __uint_as_float(v.x & 0xffff0000u);
                acc[2] += __uint_as_float(v.y << 16); acc[3] += __uint_as_float(v.y & 0xffff0000u);
                acc[4] += __uint_as_float(v.z << 16); acc[5] += __uint_as_float(v.z & 0xffff0000u);
                acc[6] += __uint_as_float(v.w << 16); acc[7] += __uint_as_float(v.w & 0xffff0000u);
            }
        }
    }
    for (int off = 1; off < 64; off <<= 1) dn += __shfl_xor(dn, off, 64);
    for (int off = 8; off < 64; off <<= 1)
#pragma unroll
        for (int i = 0; i < 8; i++) acc[i] += __shfl_xor(acc[i], off, 64);
    if (group == 0) {
        float dnr = (dn > 0.f) ? (1.0f / dn) : 0.f;
        const float4* x4 = (const float4*)x;
        float4* o4 = (float4*)out;
        float4 a = x4[(size_t)wid * 16 + gl * 2];
        float4 b = x4[(size_t)wid * 16 + gl * 2 + 1];
        float4 ra, rb2;
        ra.x = 0.5f * (a.x + dnr * acc[0]);
        ra.y = 0.5f * (a.y + dnr * acc[1]);
        ra.z = 0.5f * (a.z + dnr * acc[2]);
        ra.w = 0.5f * (a.w + dnr * acc[3]);
        rb2.x = 0.5f * (b.x + dnr * acc[4]);
        rb2.y = 0.5f * (b.y + dnr * acc[5]);
        rb2.z = 0.5f * (b.z + dnr * acc[6]);
        rb2.w = 0.5f * (b.w + dnr * acc[7]);
        o4[(size_t)wid * 16 + gl * 2] = ra;
        o4[(size_t)wid * 16 + gl * 2 + 1] = rb2;
    }
}

extern "C" void kernel_launch(void* const* d_in, const int* in_sizes, int n_in,
                              void* d_out, int out_size, void* d_ws, size_t ws_size,
                              hipStream_t stream) {
    const float* x        = (const float*)d_in[0];
    const int*   node_idx = (const int*)d_in[1];
    const int*   edge_idx = (const int*)d_in[2];
    const float* ew       = (const float*)d_in[3];
    float* out = (float*)d_out;

    char* ws = (char*)d_ws;
    unsigned short* rank_n   = (unsigned short*)(ws + 0);
    unsigned short* rank_e   = (unsigned short*)(ws + 3200000);
    int*            noff     = (int*)(ws + 6400000);
    int*            eoff     = (int*)(ws + 6800016);
    int*            node_csr = (int*)(ws + 7000032);
    int*            edge_csr = (int*)(ws + 13400032);
    // lifetime-overlapped scratch:
    unsigned short* cnt_g = (unsigned short*)(ws + 7000032);  // 9.6MB under csr; dead after replprefix
    unsigned short* rb    = (unsigned short*)(ws + 19800032); // 9.6MB; dead after fill
    int*            pn    = (int*)(ws + 29400032);            // scan scratch; dead after scan_write
    int*            pe    = pn + 32;
    int*            bn    = pn + 64;
    int*            be    = pn + 96;
    int*            tot   = (int*)(ws + 29404128);            // 600KB; dead after scan_write
    unsigned int*   ef    = (unsigned int*)(ws + 0);          // bf16, written post-fill
    unsigned int*   xh    = (unsigned int*)(ws + 19800032);   // bf16, written post-fill

    count_kernel<<<(PN + PE) * SUBR, 1024, 0, stream>>>(node_idx, edge_idx, rank_n, rank_e, cnt_g);
    replprefix_kernel<<<(N_KEYS + 255) / 256, 256, 0, stream>>>(cnt_g, rb, tot);
    scan_partial_kernel<<<N_TILES_N + N_TILES_E, 1024, 0, stream>>>(tot, pn, pe);
    scan_base_kernel<<<1, 128, 0, stream>>>(pn, pe, bn, be, noff, eoff);
    scan_write_kernel<<<N_TILES_N + N_TILES_E, 1024, 0, stream>>>(tot, bn, be, noff, eoff);
    fill_kernel<<<(M_INC + 255) / 256, 256, 0, stream>>>(node_idx, edge_idx, rank_n, rank_e,
                                                         rb, noff, eoff, node_csr, edge_csr);
    cvt_kernel<<<((N_NODES * D_HID / 8) + 255) / 256, 256, 0, stream>>>(x, xh);
    stage1_kernel<<<(N_EDGES * 64 + 255) / 256, 256, 0, stream>>>(eoff, edge_csr,
                                                                  (const uint4*)xh, (uint4*)ef);
    stage2_kernel<<<(N_NODES * 64 + 255) / 256, 256, 0, stream>>>(noff, node_csr,
                                                                  (const uint4*)ef, ew, x, out);
}